// Round 3
// baseline (19.132 us; speedup 1.0000x reference)
//
#include <hip/hip_runtime.h>
#include <math.h>

#define WINDOW_MAX 256
#define NEG -1000000.0f

// ---------------- fast path: window==256, hd==128, 512 threads ----------------
// One block per (b,h): grid (H, B). Wave-specialized: waves 0-3 do the
// q -> qk matvec chain, waves 4-7 stage the 256x128 window slice into LDS
// (two 128-row halves overlapping the two matvec phases).
// LDS xs layout: row-major 128 floats/row, 16B-chunk XOR swizzle (c ^= row&7)
// -> ds_*_b128 conflict-free for staging + score reads, scalar wsum reads too.
__global__ __launch_bounds__(512) void bca_fast(
    const float* __restrict__ content,   // (B, D)
    const float* __restrict__ cache,     // (B, T, D)
    const float* __restrict__ Wq,        // (H, 128, 128)
    const float* __restrict__ bq,        // (H, 128)
    const float* __restrict__ Wk,        // (H, 128, 128)
    const float* __restrict__ Wv,        // (H, 128, 128)
    const float* __restrict__ bv,        // (H, 128)
    const float* __restrict__ pos_param_p,
    float* __restrict__ out,             // (B, D)
    int B, int T, int D, int H, int S, int cutoff)
{
    constexpr int HD  = 128;
    constexpr int WIN = 256;

    __shared__ float xs[WIN * HD];       // 131072 B, swizzled chunks
    __shared__ float qp[2][HD];          // q partials (dq=0 half includes bq)
    __shared__ float kp[2][HD];          // qk partials
    __shared__ float scp[2][WIN];        // score partials
    __shared__ float sc[WIN];            // softmax weights
    __shared__ float wp[4][HD];          // weighted-sum partials
    __shared__ float op[4][HD];          // output partials
    __shared__ float red1[8], red2[8];

    const int tid = threadIdx.x;
    const int h = blockIdx.x, b = blockIdx.y;
    const float* cnt_g = content + (size_t)b * D + h * HD;
    const float* cb    = cache + (size_t)b * T * D + h * HD;   // + gpos*D per row

    // ---- phase 1: q matvec (waves 0-3) || stage rows 0..127 (waves 4-7) ----
    if (tid < 256) {
        const int e  = tid & (HD - 1);
        const int dq = tid >> 7;                       // wave-uniform 0/1
        const float* wq = Wq + h * HD * HD + dq * 64 * HD + e;
        const float* cg = cnt_g + dq * 64;
        float acc = (dq == 0) ? bq[h * HD + e] : 0.f;
        #pragma unroll
        for (int i = 0; i < 64; ++i)
            acc = fmaf(cg[i], wq[i * HD], acc);        // cg[i] wave-uniform -> s_load
        qp[dq][e] = acc;
    } else {
        const int t = tid - 256;
        #pragma unroll
        for (int i = 0; i < 16; ++i) {
            const int idx = i * 256 + t;               // 0..4095
            const int w = idx >> 5, f = idx & 31;      // row, 16B chunk
            const float4 v = *(const float4*)(cb + (size_t)(cutoff + w) * D + f * 4);
            const int c = f ^ (w & 7);
            *(float4*)&xs[(w << 7) + (c << 2)] = v;
        }
    }
    __syncthreads();   // B1: q parts + first half staged

    // ---- phase 2: qk matvec (waves 0-3) || stage rows 128..255 (waves 4-7) ----
    if (tid < 256) {
        const int d  = tid & (HD - 1);
        const int eh = tid >> 7;                       // wave-uniform 0/1
        const float* wk = Wk + h * HD * HD + d * HD + eh * 64;
        float acc = 0.f;
        #pragma unroll
        for (int j = 0; j < 16; ++j) {
            const float4 w4 = *(const float4*)(wk + j * 4);
            const float4 q0 = *(const float4*)&qp[0][eh * 64 + j * 4];  // broadcast
            const float4 q1 = *(const float4*)&qp[1][eh * 64 + j * 4];
            acc = fmaf(w4.x, q0.x + q1.x, acc);
            acc = fmaf(w4.y, q0.y + q1.y, acc);
            acc = fmaf(w4.z, q0.z + q1.z, acc);
            acc = fmaf(w4.w, q0.w + q1.w, acc);
        }
        kp[eh][d] = acc;
    } else {
        const int t = tid - 256;
        #pragma unroll
        for (int i = 0; i < 16; ++i) {
            const int idx = i * 256 + t;
            const int w = 128 + (idx >> 5), f = idx & 31;
            const int gpos = cutoff + w;
            const float* src = (gpos < T) ? (cb + (size_t)gpos * D) : cnt_g;
            const float4 v = *(const float4*)(src + f * 4);
            const int c = f ^ (w & 7);
            *(float4*)&xs[(w << 7) + (c << 2)] = v;
        }
    }
    __syncthreads();   // B2: qk parts + full window staged

    // ---- phase 3: scores (512 threads = 256 s x 2 d-halves) ----
    {
        const int s = tid & 255, dh = tid >> 8;        // dh wave-uniform
        const int sw = s & 7;
        float acc = 0.f;
        #pragma unroll
        for (int j = 0; j < 16; ++j) {
            const int c = (dh * 16 + j) ^ sw;
            const float4 x  = *(const float4*)&xs[(s << 7) + (c << 2)];
            const float4 k0 = *(const float4*)&kp[0][dh * 64 + j * 4];  // broadcast
            const float4 k1 = *(const float4*)&kp[1][dh * 64 + j * 4];
            acc = fmaf(x.x, k0.x + k1.x, acc);
            acc = fmaf(x.y, k0.y + k1.y, acc);
            acc = fmaf(x.z, k0.z + k1.z, acc);
            acc = fmaf(x.w, k0.w + k1.w, acc);
        }
        scp[dh][s] = acc;
    }
    __syncthreads();   // B3

    // ---- phase 4: softmax over 256 positions ----
    const float pos_param = pos_param_p[0];
    float score = -INFINITY;
    if (tid < WIN) {
        const float dot = scp[0][tid] + scp[1][tid];
        const int n = (WIN - 1) - tid;                 // distance to query
        float posb;
        if (n < 16) {
            posb = (float)n;
        } else {
            const float lc = 2.0794415416798357f;      // float32(log(8))
            int large = 16 + (int)((logf((float)n / 16.0f) / lc) * 16.0f);
            if (large > 31) large = 31;
            posb = (float)large;
        }
        // time_mask collapses to NEG everywhere (1->0, then 0->NEG); add NEG
        // to reproduce the reference's pre-softmax quantization exactly.
        score = (dot / 11.313708498984761f) - pos_param * posb + NEG;
    }
    float m = score;
    #pragma unroll
    for (int off = 32; off >= 1; off >>= 1) m = fmaxf(m, __shfl_xor(m, off));
    if ((tid & 63) == 0) red1[tid >> 6] = m;
    __syncthreads();   // B4
    float M = red1[0];
    #pragma unroll
    for (int i = 1; i < 8; ++i) M = fmaxf(M, red1[i]);

    float p = (tid < WIN) ? expf(score - M) : 0.f;
    float ssum = p;
    #pragma unroll
    for (int off = 32; off >= 1; off >>= 1) ssum += __shfl_xor(ssum, off);
    if ((tid & 63) == 0) red2[tid >> 6] = ssum;
    __syncthreads();   // B5
    float SUM = red2[0];
    #pragma unroll
    for (int i = 1; i < 8; ++i) SUM += red2[i];
    const float inv = 1.0f / SUM;
    if (tid < WIN) sc[tid] = p * inv;
    __syncthreads();   // B6

    // ---- phase 5: wsum_d = sum_s attn_s * x[s][d] (4-way s split) ----
    {
        const int d = tid & (HD - 1), sq = tid >> 7;   // sq wave-uniform 0..3
        const int dc = d >> 2, dw = d & 3;
        float acc = 0.f;
        #pragma unroll
        for (int i = 0; i < 64; ++i) {
            const int s2 = sq * 64 + i;
            const int c = dc ^ (s2 & 7);
            acc = fmaf(sc[s2], xs[(s2 << 7) + (c << 2) + dw], acc);
        }
        wp[sq][d] = acc;
    }
    __syncthreads();   // B7

    // ---- phase 6: out_e = wsum . Wv[:,e]  (4-way d split) ----
    {
        const int e = tid & (HD - 1), dq4 = tid >> 7;  // dq4 wave-uniform
        const float* wv = Wv + h * HD * HD + dq4 * 32 * HD + e;
        float acc = 0.f;
        #pragma unroll
        for (int i = 0; i < 32; ++i) {
            const int d2 = dq4 * 32 + i;               // wave-uniform
            const float ws = wp[0][d2] + wp[1][d2] + wp[2][d2] + wp[3][d2];
            acc = fmaf(ws, wv[i * HD], acc);
        }
        op[dq4][e] = acc;
    }
    __syncthreads();   // B8

    if (tid < HD) {
        const float r = op[0][tid] + op[1][tid] + op[2][tid] + op[3][tid]
                      + bv[h * HD + tid] + cnt_g[tid];
        out[(size_t)b * D + h * HD + tid] = r;
    }
}

// ---------------- generic fallback (round-1 kernel, any window<=256) ----------
__global__ __launch_bounds__(256) void bca_generic(
    const float* __restrict__ content, const float* __restrict__ cache,
    const float* __restrict__ Wq, const float* __restrict__ bq,
    const float* __restrict__ Wk, const float* __restrict__ Wv,
    const float* __restrict__ bv, const float* __restrict__ pos_param_p,
    float* __restrict__ out,
    int B, int T, int D, int H, int S, int window, int cutoff)
{
    constexpr int HD = 128;
    constexpr int XP = HD + 1;
    const int bh = blockIdx.x;
    const int b = bh / H, h = bh % H;
    const int tid = threadIdx.x;

    __shared__ float xs[WINDOW_MAX * XP];
    __shared__ float cnt_s[HD];
    __shared__ float q_s[HD];
    __shared__ float qk_s[HD];
    __shared__ float sc_s[WINDOW_MAX];
    __shared__ float part_s[256];
    __shared__ float wsum_s[HD];
    __shared__ float red_s[4];

    const float* cnt_g = content + (size_t)b * D + (size_t)h * HD;
    if (tid < HD) cnt_s[tid] = cnt_g[tid];

    const int total4 = window * (HD / 4);
    for (int idx = tid; idx < total4; idx += blockDim.x) {
        const int w = idx >> 5, f = idx & 31;
        const int gpos = cutoff + w;
        const float* src = (gpos < T)
            ? (cache + (size_t)b * T * D + (size_t)gpos * D + (size_t)h * HD)
            : cnt_g;
        const float4 v4 = *(const float4*)(src + f * 4);
        float* dst = &xs[w * XP + f * 4];
        dst[0] = v4.x; dst[1] = v4.y; dst[2] = v4.z; dst[3] = v4.w;
    }
    __syncthreads();

    if (tid < HD) {
        const float* wq = Wq + (size_t)h * HD * HD;
        float acc = 0.f;
        #pragma unroll 8
        for (int d = 0; d < HD; ++d) acc = fmaf(cnt_s[d], wq[d * HD + tid], acc);
        q_s[tid] = acc + bq[h * HD + tid];
    }
    __syncthreads();

    if (tid < HD) {
        const float* wk = Wk + (size_t)h * HD * HD + (size_t)tid * HD;
        float acc = 0.f;
        #pragma unroll 8
        for (int e = 0; e < HD; e += 4) {
            const float4 w4 = *(const float4*)(wk + e);
            acc = fmaf(w4.x, q_s[e],     acc);
            acc = fmaf(w4.y, q_s[e + 1], acc);
            acc = fmaf(w4.z, q_s[e + 2], acc);
            acc = fmaf(w4.w, q_s[e + 3], acc);
        }
        qk_s[tid] = acc;
    }
    __syncthreads();

    const float pos_param = pos_param_p[0];
    float score = -INFINITY;
    if (tid < window) {
        float acc = 0.f;
        const float* xr = &xs[tid * XP];
        #pragma unroll 8
        for (int d = 0; d < HD; ++d) acc = fmaf(qk_s[d], xr[d], acc);
        const int gpos = cutoff + tid;
        const int n = (S - 1) - gpos;
        float posb;
        if (n < 16) posb = (float)n;
        else {
            const float lc = 2.0794415416798357f;
            int large = 16 + (int)((logf((float)n / 16.0f) / lc) * 16.0f);
            if (large > 31) large = 31;
            posb = (float)large;
        }
        score = (acc / 11.313708498984761f) - pos_param * posb + NEG;
    }

    float m = score;
    #pragma unroll
    for (int off = 32; off >= 1; off >>= 1) m = fmaxf(m, __shfl_xor(m, off));
    if ((tid & 63) == 0) red_s[tid >> 6] = m;
    __syncthreads();
    const int nw = blockDim.x >> 6;
    float M = red_s[0];
    for (int i = 1; i < nw; ++i) M = fmaxf(M, red_s[i]);

    float p = (tid < window) ? expf(score - M) : 0.f;
    float ssum = p;
    #pragma unroll
    for (int off = 32; off >= 1; off >>= 1) ssum += __shfl_xor(ssum, off);
    __syncthreads();
    if ((tid & 63) == 0) red_s[tid >> 6] = ssum;
    __syncthreads();
    float SUM = 0.f;
    for (int i = 0; i < nw; ++i) SUM += red_s[i];
    const float inv = 1.0f / SUM;
    if (tid < window) sc_s[tid] = p * inv;
    __syncthreads();

    {
        const int d = tid & (HD - 1), half = tid >> 7;
        const int s0 = half * (window >> 1), s1 = s0 + (window >> 1);
        float acc = 0.f;
        for (int s = s0; s < s1; ++s) acc = fmaf(sc_s[s], xs[s * XP + d], acc);
        part_s[tid] = acc;
    }
    __syncthreads();
    if (tid < HD) wsum_s[tid] = part_s[tid] + part_s[tid + HD];
    __syncthreads();

    {
        const int e = tid & (HD - 1), dh = tid >> 7;
        const float* wv = Wv + (size_t)h * HD * HD;
        float acc = 0.f;
        for (int d = dh * 64; d < dh * 64 + 64; ++d)
            acc = fmaf(wsum_s[d], wv[d * HD + e], acc);
        part_s[tid] = acc;
    }
    __syncthreads();
    if (tid < HD) {
        const float r = part_s[tid] + part_s[tid + HD]
                      + bv[h * HD + tid] + cnt_g[tid];
        out[(size_t)b * D + (size_t)h * HD + tid] = r;
    }
}

extern "C" void kernel_launch(void* const* d_in, const int* in_sizes, int n_in,
                              void* d_out, int out_size, void* d_ws, size_t ws_size,
                              hipStream_t stream) {
    // inputs: 0:t 1:content_t 2:time_mask 3:cache 4:speakers 5:Wq 6:bq 7:Wk 8:bk 9:Wv 10:bv 11:pos_param
    const float* content = (const float*)d_in[1];
    const float* cache   = (const float*)d_in[3];
    const float* Wq      = (const float*)d_in[5];
    const float* bq      = (const float*)d_in[6];
    const float* Wk      = (const float*)d_in[7];
    const float* Wv      = (const float*)d_in[9];
    const float* bv      = (const float*)d_in[10];
    const float* posp    = (const float*)d_in[11];

    const int D  = in_sizes[6];
    const int B  = in_sizes[1] / D;
    const int hd = in_sizes[5] / D;
    const int H  = D / hd;
    const int T  = in_sizes[3] / (B * D);
    const int S  = T + 1;
    const int window = (S < WINDOW_MAX) ? S : WINDOW_MAX;
    const int cutoff = S - window;

    if (window == WINDOW_MAX && hd == 128) {
        dim3 grid(H, B), block(512);
        hipLaunchKernelGGL(bca_fast, grid, block, 0, stream,
                           content, cache, Wq, bq, Wk, Wv, bv, posp,
                           (float*)d_out, B, T, D, H, S, cutoff);
    } else {
        dim3 grid(B * H), block(256);
        hipLaunchKernelGGL(bca_generic, grid, block, 0, stream,
                           content, cache, Wq, bq, Wk, Wv, bv, posp,
                           (float*)d_out, B, T, D, H, S, window, cutoff);
    }
}

// Round 4
// 15.408 us; speedup vs baseline: 1.2417x; 1.2417x over previous
//
#include <hip/hip_runtime.h>
#include <math.h>

#define WINDOW_MAX 256
#define NEG -1000000.0f

typedef __attribute__((address_space(1))) const float gfloat;
typedef __attribute__((address_space(3))) float lfloat;

// ---------------- fast path: window==256, hd==128, 512 threads ----------------
// One block per (b,h): grid (H, B) -> same-h blocks share an XCD (id%8==h%8),
// so the 192KB/head weight reads are L2-local across the 8 batch blocks.
// All global loads are issued at kernel entry (Wk/Wv/content/bv in registers,
// window via async global_load_lds with pre-swizzled per-lane source), so the
// kernel pays ~one HBM latency round total, then pure LDS/VALU phases.
// xs layout: 128 floats/row, 16B-chunk XOR swizzle (lds chunk c = f ^ (row&7))
// -> conflict-free ds_*_b128 for staging writes + score reads + wsum reads.
__global__ __launch_bounds__(512, 2) void bca_fast(
    const float* __restrict__ content,   // (B, D)
    const float* __restrict__ cache,     // (B, T, D)
    const float* __restrict__ Wq,        // (H, 128, 128)
    const float* __restrict__ bq,        // (H, 128)
    const float* __restrict__ Wk,        // (H, 128, 128)
    const float* __restrict__ Wv,        // (H, 128, 128)
    const float* __restrict__ bv,        // (H, 128)
    const float* __restrict__ pos_param_p,
    float* __restrict__ out,             // (B, D)
    int B, int T, int D, int H, int S, int cutoff)
{
    constexpr int HD  = 128;
    constexpr int WIN = 256;

    __shared__ float xs[WIN * HD];       // 131072 B, swizzled chunks
    __shared__ float qp[2][HD];          // q partials (g2=0 half includes bq)
    __shared__ float kp[2][HD];          // qk partials
    __shared__ float scp[2][WIN];        // score partials
    __shared__ float sc[WIN];            // UNNORMALIZED softmax weights (p)
    __shared__ float wp[4][HD];          // weighted-sum partials
    __shared__ float op[4][HD];          // output partials
    __shared__ float red1[8], red2[8];

    const int tid = threadIdx.x;
    const int h = blockIdx.x, b = blockIdx.y;
    const float* cnt_g = content + (size_t)b * D + h * HD;
    const float* cb    = cache + (size_t)b * T * D + h * HD;

    // ---- issue ALL global loads up front ----
    const float pos_param = pos_param_p[0];
    const int e128 = tid & 127;
    const int g4   = tid >> 7;                         // 0..3, wave-uniform
    float creg = 0.f, bvreg = 0.f;
    if (tid < HD) { creg = cnt_g[tid]; bvreg = bv[h * HD + tid]; }

    // Wv prefetch for the output matvec (thread (e128, g4) covers d = g4*32..+31)
    float wvreg[32];
    {
        const float* wvp = Wv + h * HD * HD + (g4 * 32) * HD + e128;
        #pragma unroll
        for (int i = 0; i < 32; ++i) wvreg[i] = wvp[i * HD];
    }

    if (tid < 256) {
        const int g2 = g4;                             // 0/1 here
        // Wk prefetch: thread (d=e128, eh=g2) holds Wk[d][eh*64 .. +63]
        float4 wk4[16];
        {
            const float* wkp = Wk + h * HD * HD + e128 * HD + g2 * 64;
            #pragma unroll
            for (int j = 0; j < 16; ++j) wk4[j] = *(const float4*)(wkp + j * 4);
        }
        // q partial: q[e] = sum_d cnt[d] * Wq[d][e] (+ bq on g2==0 half)
        const float* wqp = Wq + h * HD * HD + (g2 * 64) * HD + e128;
        const float* cg  = cnt_g + g2 * 64;            // wave-uniform reads
        float acc = (g2 == 0) ? bq[h * HD + e128] : 0.f;
        #pragma unroll
        for (int i = 0; i < 64; ++i)
            acc = fmaf(cg[i], wqp[i * HD], acc);
        qp[g2][e128] = acc;

        __syncthreads();   // B1: q partials + full window staged

        // qk: thread (d=e128, eh=g2): qk_d partial over e = g2*64..+63
        float a2 = 0.f;
        #pragma unroll
        for (int j = 0; j < 16; ++j) {
            const float4 q0 = *(const float4*)&qp[0][g2 * 64 + j * 4]; // broadcast
            const float4 q1 = *(const float4*)&qp[1][g2 * 64 + j * 4];
            a2 = fmaf(wk4[j].x, q0.x + q1.x, a2);
            a2 = fmaf(wk4[j].y, q0.y + q1.y, a2);
            a2 = fmaf(wk4[j].z, q0.z + q1.z, a2);
            a2 = fmaf(wk4[j].w, q0.w + q1.w, a2);
        }
        kp[g2][e128] = a2;
    } else {
        // staging waves 4..7: 64 rows each, 32 async 1KB global_load_lds.
        // LDS dest linear (base + lane*16); per-lane source pre-swizzled so
        // lds chunk c holds global chunk f = c ^ (row&7).
        const int sw   = (tid >> 6) - 4;               // 0..3
        const int lane = tid & 63;
        #pragma unroll
        for (int i = 0; i < 32; ++i) {
            const int w    = sw * 64 + i * 2;          // wave-uniform row pair
            const int row  = w + (lane >> 5);
            const int f    = (lane & 31) ^ (row & 7);
            const int gpos = cutoff + row;
            const float* src = (gpos < T) ? (cb + (size_t)gpos * D + f * 4)
                                          : (cnt_g + f * 4);
            __builtin_amdgcn_global_load_lds((gfloat*)src, (lfloat*)&xs[w << 7],
                                             16, 0, 0);
        }
        __syncthreads();   // B1 (drains vmcnt -> xs complete)
    }
    __syncthreads();       // B2: kp ready

    // ---- scores (512 threads = 256 s x 2 d-halves) ----
    {
        const int s = tid & 255, dh = tid >> 8;        // dh wave-uniform
        const int swz = s & 7;
        float acc = 0.f;
        #pragma unroll
        for (int j = 0; j < 16; ++j) {
            const int c = (dh * 16 + j) ^ swz;
            const float4 x  = *(const float4*)&xs[(s << 7) + (c << 2)];
            const float4 k0 = *(const float4*)&kp[0][dh * 64 + j * 4];  // broadcast
            const float4 k1 = *(const float4*)&kp[1][dh * 64 + j * 4];
            acc = fmaf(x.x, k0.x + k1.x, acc);
            acc = fmaf(x.y, k0.y + k1.y, acc);
            acc = fmaf(x.z, k0.z + k1.z, acc);
            acc = fmaf(x.w, k0.w + k1.w, acc);
        }
        scp[dh][s] = acc;
    }
    __syncthreads();   // B3

    // ---- softmax over 256 positions (unnormalized p; 1/SUM folded at end) ----
    float score = -INFINITY;
    if (tid < WIN) {
        const float dot = scp[0][tid] + scp[1][tid];
        const int n = (WIN - 1) - tid;                 // distance to query
        float posb;
        if (n < 16) {
            posb = (float)n;
        } else {
            const float lc = 2.0794415416798357f;      // float32(log(8))
            int large = 16 + (int)((logf((float)n / 16.0f) / lc) * 16.0f);
            if (large > 31) large = 31;
            posb = (float)large;
        }
        // time_mask collapses to NEG everywhere (1->0, then 0->NEG); add NEG
        // to reproduce the reference's pre-softmax quantization exactly.
        score = (dot / 11.313708498984761f) - pos_param * posb + NEG;
    }
    float m = score;
    #pragma unroll
    for (int off = 32; off >= 1; off >>= 1) m = fmaxf(m, __shfl_xor(m, off));
    if ((tid & 63) == 0) red1[tid >> 6] = m;
    __syncthreads();   // B4
    float M = red1[0];
    #pragma unroll
    for (int i = 1; i < 8; ++i) M = fmaxf(M, red1[i]);

    float p = (tid < WIN) ? expf(score - M) : 0.f;
    if (tid < WIN) sc[tid] = p;
    float ssum = p;
    #pragma unroll
    for (int off = 32; off >= 1; off >>= 1) ssum += __shfl_xor(ssum, off);
    if ((tid & 63) == 0) red2[tid >> 6] = ssum;
    __syncthreads();   // B5: sc + red2 ready

    // ---- wsum_d = sum_s p_s * x[s][d] (4-way s split, unnormalized) ----
    {
        const int d = e128, sq = g4;                   // sq wave-uniform 0..3
        const int dc = d >> 2, dw = d & 3;
        float acc = 0.f;
        #pragma unroll
        for (int i = 0; i < 64; ++i) {
            const int s2 = sq * 64 + i;
            const int c = dc ^ (s2 & 7);
            acc = fmaf(sc[s2], xs[(s2 << 7) + (c << 2) + dw], acc);
        }
        wp[sq][d] = acc;
    }
    __syncthreads();   // B6

    // ---- out_e = wsum . Wv[:,e] (4-way d split, Wv already in registers) ----
    {
        float acc = 0.f;
        #pragma unroll
        for (int i = 0; i < 32; ++i) {
            const int d2 = g4 * 32 + i;                // wave-uniform
            const float ws = wp[0][d2] + wp[1][d2] + wp[2][d2] + wp[3][d2];
            acc = fmaf(ws, wvreg[i], acc);
        }
        op[g4][e128] = acc;
    }
    __syncthreads();   // B7

    if (tid < HD) {
        float SUM = red2[0];
        #pragma unroll
        for (int i = 1; i < 8; ++i) SUM += red2[i];
        const float r = (op[0][tid] + op[1][tid] + op[2][tid] + op[3][tid])
                        * (1.0f / SUM) + bvreg + creg;
        out[(size_t)b * D + h * HD + tid] = r;
    }
}

// ---------------- generic fallback (any window<=256) ----------
__global__ __launch_bounds__(256) void bca_generic(
    const float* __restrict__ content, const float* __restrict__ cache,
    const float* __restrict__ Wq, const float* __restrict__ bq,
    const float* __restrict__ Wk, const float* __restrict__ Wv,
    const float* __restrict__ bv, const float* __restrict__ pos_param_p,
    float* __restrict__ out,
    int B, int T, int D, int H, int S, int window, int cutoff)
{
    constexpr int HD = 128;
    constexpr int XP = HD + 1;
    const int bh = blockIdx.x;
    const int b = bh / H, h = bh % H;
    const int tid = threadIdx.x;

    __shared__ float xs[WINDOW_MAX * XP];
    __shared__ float cnt_s[HD];
    __shared__ float q_s[HD];
    __shared__ float qk_s[HD];
    __shared__ float sc_s[WINDOW_MAX];
    __shared__ float part_s[256];
    __shared__ float wsum_s[HD];
    __shared__ float red_s[4];

    const float* cnt_g = content + (size_t)b * D + (size_t)h * HD;
    if (tid < HD) cnt_s[tid] = cnt_g[tid];

    const int total4 = window * (HD / 4);
    for (int idx = tid; idx < total4; idx += blockDim.x) {
        const int w = idx >> 5, f = idx & 31;
        const int gpos = cutoff + w;
        const float* src = (gpos < T)
            ? (cache + (size_t)b * T * D + (size_t)gpos * D + (size_t)h * HD)
            : cnt_g;
        const float4 v4 = *(const float4*)(src + f * 4);
        float* dst = &xs[w * XP + f * 4];
        dst[0] = v4.x; dst[1] = v4.y; dst[2] = v4.z; dst[3] = v4.w;
    }
    __syncthreads();

    if (tid < HD) {
        const float* wq = Wq + (size_t)h * HD * HD;
        float acc = 0.f;
        #pragma unroll 8
        for (int d = 0; d < HD; ++d) acc = fmaf(cnt_s[d], wq[d * HD + tid], acc);
        q_s[tid] = acc + bq[h * HD + tid];
    }
    __syncthreads();

    if (tid < HD) {
        const float* wk = Wk + (size_t)h * HD * HD + (size_t)tid * HD;
        float acc = 0.f;
        #pragma unroll 8
        for (int e = 0; e < HD; e += 4) {
            const float4 w4 = *(const float4*)(wk + e);
            acc = fmaf(w4.x, q_s[e],     acc);
            acc = fmaf(w4.y, q_s[e + 1], acc);
            acc = fmaf(w4.z, q_s[e + 2], acc);
            acc = fmaf(w4.w, q_s[e + 3], acc);
        }
        qk_s[tid] = acc;
    }
    __syncthreads();

    const float pos_param = pos_param_p[0];
    float score = -INFINITY;
    if (tid < window) {
        float acc = 0.f;
        const float* xr = &xs[tid * XP];
        #pragma unroll 8
        for (int d = 0; d < HD; ++d) acc = fmaf(qk_s[d], xr[d], acc);
        const int gpos = cutoff + tid;
        const int n = (S - 1) - gpos;
        float posb;
        if (n < 16) posb = (float)n;
        else {
            const float lc = 2.0794415416798357f;
            int large = 16 + (int)((logf((float)n / 16.0f) / lc) * 16.0f);
            if (large > 31) large = 31;
            posb = (float)large;
        }
        score = (acc / 11.313708498984761f) - pos_param * posb + NEG;
    }

    float m = score;
    #pragma unroll
    for (int off = 32; off >= 1; off >>= 1) m = fmaxf(m, __shfl_xor(m, off));
    if ((tid & 63) == 0) red_s[tid >> 6] = m;
    __syncthreads();
    const int nw = blockDim.x >> 6;
    float M = red_s[0];
    for (int i = 1; i < nw; ++i) M = fmaxf(M, red_s[i]);

    float p = (tid < window) ? expf(score - M) : 0.f;
    float ssum = p;
    #pragma unroll
    for (int off = 32; off >= 1; off >>= 1) ssum += __shfl_xor(ssum, off);
    __syncthreads();
    if ((tid & 63) == 0) red_s[tid >> 6] = ssum;
    __syncthreads();
    float SUM = 0.f;
    for (int i = 0; i < nw; ++i) SUM += red_s[i];
    const float inv = 1.0f / SUM;
    if (tid < window) sc_s[tid] = p * inv;
    __syncthreads();

    {
        const int d = tid & (HD - 1), half = tid >> 7;
        const int s0 = half * (window >> 1), s1 = s0 + (window >> 1);
        float acc = 0.f;
        for (int s = s0; s < s1; ++s) acc = fmaf(sc_s[s], xs[s * XP + d], acc);
        part_s[tid] = acc;
    }
    __syncthreads();
    if (tid < HD) wsum_s[tid] = part_s[tid] + part_s[tid + HD];
    __syncthreads();

    {
        const int e = tid & (HD - 1), dh = tid >> 7;
        const float* wv = Wv + (size_t)h * HD * HD;
        float acc = 0.f;
        for (int d = dh * 64; d < dh * 64 + 64; ++d)
            acc = fmaf(wsum_s[d], wv[d * HD + e], acc);
        part_s[tid] = acc;
    }
    __syncthreads();
    if (tid < HD) {
        const float r = part_s[tid] + part_s[tid + HD]
                      + bv[h * HD + tid] + cnt_g[tid];
        out[(size_t)b * D + (size_t)h * HD + tid] = r;
    }
}

extern "C" void kernel_launch(void* const* d_in, const int* in_sizes, int n_in,
                              void* d_out, int out_size, void* d_ws, size_t ws_size,
                              hipStream_t stream) {
    // inputs: 0:t 1:content_t 2:time_mask 3:cache 4:speakers 5:Wq 6:bq 7:Wk 8:bk 9:Wv 10:bv 11:pos_param
    const float* content = (const float*)d_in[1];
    const float* cache   = (const float*)d_in[3];
    const float* Wq      = (const float*)d_in[5];
    const float* bq      = (const float*)d_in[6];
    const float* Wk      = (const float*)d_in[7];
    const float* Wv      = (const float*)d_in[9];
    const float* bv      = (const float*)d_in[10];
    const float* posp    = (const float*)d_in[11];

    const int D  = in_sizes[6];
    const int B  = in_sizes[1] / D;
    const int hd = in_sizes[5] / D;
    const int H  = D / hd;
    const int T  = in_sizes[3] / (B * D);
    const int S  = T + 1;
    const int window = (S < WINDOW_MAX) ? S : WINDOW_MAX;
    const int cutoff = S - window;

    if (window == WINDOW_MAX && hd == 128) {
        dim3 grid(H, B), block(512);
        hipLaunchKernelGGL(bca_fast, grid, block, 0, stream,
                           content, cache, Wq, bq, Wk, Wv, bv, posp,
                           (float*)d_out, B, T, D, H, S, cutoff);
    } else {
        dim3 grid(B * H), block(256);
        hipLaunchKernelGGL(bca_generic, grid, block, 0, stream,
                           content, cache, Wq, bq, Wk, Wv, bv, posp,
                           (float*)d_out, B, T, D, H, S, window, cutoff);
    }
}